// Round 1
// baseline (363.900 us; speedup 1.0000x reference)
//
#include <hip/hip_runtime.h>

typedef _Float16 half8 __attribute__((ext_vector_type(8)));
typedef _Float16 half4v __attribute__((ext_vector_type(4)));
typedef float f32x4 __attribute__((ext_vector_type(4)));

__device__ __forceinline__ void gload_lds16(const _Float16* g, _Float16* l) {
    __builtin_amdgcn_global_load_lds(
        (const __attribute__((address_space(1))) void*)g,
        (__attribute__((address_space(3))) void*)l,
        16, 0, 0);
}

// ---------------- fp32 -> fp16 convert (vectorized) ----------------
__global__ void cvt_f32_f16(const float* __restrict__ src, _Float16* __restrict__ dst, int n4) {
    int i = blockIdx.x * blockDim.x + threadIdx.x;
    if (i >= n4) return;
    f32x4 v = ((const f32x4*)src)[i];
    half4v h;
    h[0] = (_Float16)v[0]; h[1] = (_Float16)v[1];
    h[2] = (_Float16)v[2]; h[3] = (_Float16)v[3];
    ((half4v*)dst)[i] = h;
}

// ---------------- NT GEMM: C[M,N] = A[M,K] * B[N,K]^T ----------------
// M=8192, N=1024, K=1024. 128x128 tile, BK=32, 256 threads (4 waves, 2x2),
// each wave 64x64 (4x4 fragments of 16x16), mfma_f32_16x16x32_f16.
// MODE 0: QKV — half out, [b,h,s,d] layout, scale 0.125 on z==0, B/out selected by blockIdx.z
// MODE 1: O-proj — float out, row-major [8192,1024]
template<int MODE>
__global__ void gemm_nt(const _Float16* __restrict__ A,
                        const _Float16* __restrict__ Wbase,
                        void* __restrict__ outbase)
{
    constexpr int K = 1024;
    __shared__ _Float16 As[2][128 * 32];
    __shared__ _Float16 Bs[2][128 * 32];

    const int tid  = threadIdx.x;
    const int lane = tid & 63;
    const int w    = tid >> 6;
    const int wr   = w >> 1, wc = w & 1;
    const int lr   = lane & 15, lg = lane >> 4;
    const int brow = blockIdx.x * 128;
    const int bcol = blockIdx.y * 128;

    const _Float16* Bw = Wbase + (MODE == 0 ? (size_t)blockIdx.z * (1024u * 1024u) : 0);

    // staging: wave-linear LDS (base + lane*16B); row = w*16 + lane/4 (+64), col = (lane&3)*8
    const int srow = w * 16 + (lane >> 2);
    const int scol = (lane & 3) * 8;
    const _Float16* Ag = A  + (size_t)(brow + srow) * K + scol;
    const _Float16* Bg = Bw + (size_t)(bcol + srow) * K + scol;

    auto stage = [&](int buf, int kt) {
        const _Float16* a0 = Ag + kt * 32;
        const _Float16* b0 = Bg + kt * 32;
        gload_lds16(a0,           &As[buf][w * 512]);
        gload_lds16(a0 + 64 * K,  &As[buf][w * 512 + 2048]);
        gload_lds16(b0,           &Bs[buf][w * 512]);
        gload_lds16(b0 + 64 * K,  &Bs[buf][w * 512 + 2048]);
    };

    f32x4 acc[4][4] = {};
    stage(0, 0);
    __syncthreads();

    for (int kt = 0; kt < K / 32; ++kt) {
        const int cur = kt & 1;
        if (kt + 1 < K / 32) stage(cur ^ 1, kt + 1);
        half8 af[4], bf[4];
#pragma unroll
        for (int mi = 0; mi < 4; ++mi)
            af[mi] = *(const half8*)&As[cur][(wr * 64 + mi * 16 + lr) * 32 + lg * 8];
#pragma unroll
        for (int ni = 0; ni < 4; ++ni)
            bf[ni] = *(const half8*)&Bs[cur][(wc * 64 + ni * 16 + lr) * 32 + lg * 8];
#pragma unroll
        for (int mi = 0; mi < 4; ++mi)
#pragma unroll
            for (int ni = 0; ni < 4; ++ni)
                acc[mi][ni] = __builtin_amdgcn_mfma_f32_16x16x32_f16(af[mi], bf[ni], acc[mi][ni], 0, 0, 0);
        __syncthreads();
    }

    if (MODE == 0) {
        _Float16* outp = (_Float16*)outbase + (size_t)blockIdx.z * (8192u * 1024u);
        const float scale = (blockIdx.z == 0) ? 0.125f : 1.0f;
#pragma unroll
        for (int mi = 0; mi < 4; ++mi)
#pragma unroll
            for (int ni = 0; ni < 4; ++ni)
#pragma unroll
                for (int r = 0; r < 4; ++r) {
                    int row = brow + wr * 64 + mi * 16 + lg * 4 + r;   // 0..8191 = b*2048+s
                    int col = bcol + wc * 64 + ni * 16 + lr;           // 0..1023 = h*64+d
                    int b = row >> 11, s = row & 2047;
                    int h = col >> 6,  d = col & 63;
                    outp[(((size_t)b * 16 + h) * 2048 + s) * 64 + d] = (_Float16)(acc[mi][ni][r] * scale);
                }
    } else {
        float* outp = (float*)outbase;
#pragma unroll
        for (int mi = 0; mi < 4; ++mi)
#pragma unroll
            for (int ni = 0; ni < 4; ++ni)
#pragma unroll
                for (int r = 0; r < 4; ++r) {
                    int row = brow + wr * 64 + mi * 16 + lg * 4 + r;
                    int col = bcol + wc * 64 + ni * 16 + lr;
                    outp[(size_t)row * 1024 + col] = acc[mi][ni][r];
                }
    }
}

// ---------------- flash attention ----------------
// grid (32, 64): x = q-block (64 rows), y = b*16+h. 256 threads (4 waves),
// each wave owns 16 q-rows. KV tiles of 64 keys staged in LDS (padded rows).
__global__ void attn_kernel(const _Float16* __restrict__ Q,
                            const _Float16* __restrict__ Kx,
                            const _Float16* __restrict__ Vx,
                            _Float16* __restrict__ Ctx)
{
    __shared__ _Float16 Ks [64 * 72];      // [key][d] padded
    __shared__ _Float16 Vts[64 * 72];      // [d][key] padded (transposed)
    __shared__ _Float16 Ps [4][16 * 72];   // per-wave P [q][key] padded

    const int tid = threadIdx.x, lane = tid & 63, w = tid >> 6;
    const int lr = lane & 15, lg = lane >> 4;
    const int bh = blockIdx.y;
    const int qblk = blockIdx.x;

    const _Float16* Qp = Q  + ((size_t)bh * 2048 + qblk * 64) * 64;
    const _Float16* Kp = Kx + (size_t)bh * 2048 * 64;
    const _Float16* Vp = Vx + (size_t)bh * 2048 * 64;

    // Q fragments (A-operand), already scaled by 1/8 at GEMM write
    half8 qf[2];
#pragma unroll
    for (int kk = 0; kk < 2; ++kk)
        qf[kk] = *(const half8*)(Qp + (w * 16 + lr) * 64 + kk * 32 + lg * 8);

    f32x4 cacc[4] = {};
    float mrun[4] = {-1e30f, -1e30f, -1e30f, -1e30f};
    float lrun[4] = {};

    const int ldr = tid >> 2;         // 0..63 (key row / V row)
    const int ldc = (tid & 3) * 16;   // 0,16,32,48

    for (int t = 0; t < 32; ++t) {
        __syncthreads();
        {
            const _Float16* Kg = Kp + (size_t)t * 64 * 64 + ldr * 64 + ldc;
            const _Float16* Vg = Vp + (size_t)t * 64 * 64 + ldr * 64 + ldc;
            half8 k0 = *(const half8*)(Kg);
            half8 k1 = *(const half8*)(Kg + 8);
            *(half8*)&Ks[ldr * 72 + ldc]     = k0;
            *(half8*)&Ks[ldr * 72 + ldc + 8] = k1;
            half8 v0 = *(const half8*)(Vg);
            half8 v1 = *(const half8*)(Vg + 8);
#pragma unroll
            for (int j = 0; j < 8; ++j) Vts[(ldc + j) * 72 + ldr]     = v0[j];
#pragma unroll
            for (int j = 0; j < 8; ++j) Vts[(ldc + 8 + j) * 72 + ldr] = v1[j];
        }
        __syncthreads();

        // S = Q K^T  (16x64 per wave)
        f32x4 sf[4];
#pragma unroll
        for (int ni = 0; ni < 4; ++ni) {
            half8 kb0 = *(const half8*)&Ks[(ni * 16 + lr) * 72 + lg * 8];
            half8 kb1 = *(const half8*)&Ks[(ni * 16 + lr) * 72 + 32 + lg * 8];
            f32x4 z = {};
            z = __builtin_amdgcn_mfma_f32_16x16x32_f16(qf[0], kb0, z, 0, 0, 0);
            z = __builtin_amdgcn_mfma_f32_16x16x32_f16(qf[1], kb1, z, 0, 0, 0);
            sf[ni] = z;
        }

        // online softmax: lane holds rows q = lg*4+r, cols ni*16+lr
        float rmax[4];
#pragma unroll
        for (int r = 0; r < 4; ++r)
            rmax[r] = fmaxf(fmaxf(sf[0][r], sf[1][r]), fmaxf(sf[2][r], sf[3][r]));
#pragma unroll
        for (int off = 1; off < 16; off <<= 1)
#pragma unroll
            for (int r = 0; r < 4; ++r)
                rmax[r] = fmaxf(rmax[r], __shfl_xor(rmax[r], off, 64));

        float resc[4], rsum[4];
#pragma unroll
        for (int r = 0; r < 4; ++r) {
            float mnew = fmaxf(mrun[r], rmax[r]);
            resc[r] = __expf(mrun[r] - mnew);
            mrun[r] = mnew;
            rsum[r] = 0.f;
        }
#pragma unroll
        for (int ni = 0; ni < 4; ++ni)
#pragma unroll
            for (int r = 0; r < 4; ++r) {
                float p = __expf(sf[ni][r] - mrun[r]);
                sf[ni][r] = p;
                rsum[r] += p;
            }
#pragma unroll
        for (int off = 1; off < 16; off <<= 1)
#pragma unroll
            for (int r = 0; r < 4; ++r)
                rsum[r] += __shfl_xor(rsum[r], off, 64);
#pragma unroll
        for (int r = 0; r < 4; ++r)
            lrun[r] = lrun[r] * resc[r] + rsum[r];
#pragma unroll
        for (int ni = 0; ni < 4; ++ni)
#pragma unroll
            for (int r = 0; r < 4; ++r)
                cacc[ni][r] *= resc[r];

        // P -> LDS (fp16), per-wave private region; then PV
#pragma unroll
        for (int ni = 0; ni < 4; ++ni)
#pragma unroll
            for (int r = 0; r < 4; ++r)
                Ps[w][(lg * 4 + r) * 72 + ni * 16 + lr] = (_Float16)sf[ni][r];

        half8 pa0 = *(const half8*)&Ps[w][lr * 72 + lg * 8];
        half8 pa1 = *(const half8*)&Ps[w][lr * 72 + 32 + lg * 8];
#pragma unroll
        for (int ni = 0; ni < 4; ++ni) {
            half8 vb0 = *(const half8*)&Vts[(ni * 16 + lr) * 72 + lg * 8];
            half8 vb1 = *(const half8*)&Vts[(ni * 16 + lr) * 72 + 32 + lg * 8];
            cacc[ni] = __builtin_amdgcn_mfma_f32_16x16x32_f16(pa0, vb0, cacc[ni], 0, 0, 0);
            cacc[ni] = __builtin_amdgcn_mfma_f32_16x16x32_f16(pa1, vb1, cacc[ni], 0, 0, 0);
        }
    }

    float inv[4];
#pragma unroll
    for (int r = 0; r < 4; ++r) inv[r] = 1.0f / lrun[r];
    // ctx layout [b][s][h*64+d] fp16 (A-matrix of O-proj GEMM)
    _Float16* Cp = Ctx + ((size_t)(bh >> 4) * 2048 + qblk * 64 + w * 16) * 1024 + (bh & 15) * 64;
#pragma unroll
    for (int ni = 0; ni < 4; ++ni)
#pragma unroll
        for (int r = 0; r < 4; ++r)
            Cp[(size_t)(lg * 4 + r) * 1024 + ni * 16 + lr] = (_Float16)(cacc[ni][r] * inv[r]);
}

extern "C" void kernel_launch(void* const* d_in, const int* in_sizes, int n_in,
                              void* d_out, int out_size, void* d_ws, size_t ws_size,
                              hipStream_t stream)
{
    const float* X  = (const float*)d_in[0];
    const float* Wq = (const float*)d_in[1];
    const float* Wk = (const float*)d_in[2];
    const float* Wv = (const float*)d_in[3];
    const float* Wo = (const float*)d_in[4];

    // workspace layout (halves): Xh[8M] | Wh[4M] | QKV[24M]; Ctx aliases Xh
    if (ws_size < (size_t)(8 + 4 + 24) * 1024 * 1024 * 2) return;
    _Float16* Xh  = (_Float16*)d_ws;
    _Float16* Wh  = Xh + (size_t)8 * 1024 * 1024;
    _Float16* QKV = Wh + (size_t)4 * 1024 * 1024;
    _Float16* Ctx = Xh;  // reuse after QKV GEMM has consumed Xh

    cvt_f32_f16<<<8192, 256, 0, stream>>>(X,  Xh,            2097152);
    cvt_f32_f16<<<1024, 256, 0, stream>>>(Wq, Wh,            262144);
    cvt_f32_f16<<<1024, 256, 0, stream>>>(Wk, Wh + 1048576,  262144);
    cvt_f32_f16<<<1024, 256, 0, stream>>>(Wv, Wh + 2097152,  262144);
    cvt_f32_f16<<<1024, 256, 0, stream>>>(Wo, Wh + 3145728,  262144);

    // Q,K,V projections (z = 0,1,2), scale folded into Q
    gemm_nt<0><<<dim3(64, 8, 3), 256, 0, stream>>>(Xh, Wh, QKV);

    // flash attention
    attn_kernel<<<dim3(32, 64), 256, 0, stream>>>(QKV, QKV + 8388608, QKV + 16777216, Ctx);

    // output projection -> fp32 d_out
    gemm_nt<1><<<dim3(64, 8, 1), 256, 0, stream>>>(Ctx, Wh + 3145728, d_out);
}

// Round 3
// 272.519 us; speedup vs baseline: 1.3353x; 1.3353x over previous
//
#include <hip/hip_runtime.h>

typedef _Float16 half8 __attribute__((ext_vector_type(8)));
typedef _Float16 half4v __attribute__((ext_vector_type(4)));
typedef float f32x4 __attribute__((ext_vector_type(4)));

__device__ __forceinline__ void gload_lds16(const _Float16* g, _Float16* l) {
    __builtin_amdgcn_global_load_lds(
        (const __attribute__((address_space(1))) void*)g,
        (__attribute__((address_space(3))) void*)l,
        16, 0, 0);
}

// ---------------- fp32 -> fp16 convert (vectorized) ----------------
__global__ void cvt_f32_f16(const float* __restrict__ src, _Float16* __restrict__ dst, int n4) {
    int i = blockIdx.x * blockDim.x + threadIdx.x;
    if (i >= n4) return;
    f32x4 v = ((const f32x4*)src)[i];
    half4v h;
    h[0] = (_Float16)v[0]; h[1] = (_Float16)v[1];
    h[2] = (_Float16)v[2]; h[3] = (_Float16)v[3];
    ((half4v*)dst)[i] = h;
}

// ---------------- NT GEMM: C[M,N] = A[M,K] * B[N,K]^T ----------------
// M=8192, N=1024, K=1024. 128x128 tile, BK=32, 256 threads (4 waves, 2x2).
// MODE 0: QKV — half out; z=0: Q [b,h,s,d] scaled by (1/8)*log2e; z=1: K [b,h,s,d];
//         z=2: V TRANSPOSED [b,h,d,s]
// MODE 1: O-proj — float out, row-major [8192,1024]
template<int MODE>
__global__ void gemm_nt(const _Float16* __restrict__ A,
                        const _Float16* __restrict__ Wbase,
                        void* __restrict__ outbase)
{
    constexpr int K = 1024;
    __shared__ _Float16 As[2][128 * 32];
    __shared__ _Float16 Bs[2][128 * 32];

    const int tid  = threadIdx.x;
    const int lane = tid & 63;
    const int w    = tid >> 6;
    const int wr   = w >> 1, wc = w & 1;
    const int lr   = lane & 15, lg = lane >> 4;
    const int brow = blockIdx.x * 128;
    const int bcol = blockIdx.y * 128;

    const _Float16* Bw = Wbase + (MODE == 0 ? (size_t)blockIdx.z * (1024u * 1024u) : 0);

    const int srow = w * 16 + (lane >> 2);
    const int scol = (lane & 3) * 8;
    const _Float16* Ag = A  + (size_t)(brow + srow) * K + scol;
    const _Float16* Bg = Bw + (size_t)(bcol + srow) * K + scol;

    auto stage = [&](int buf, int kt) {
        const _Float16* a0 = Ag + kt * 32;
        const _Float16* b0 = Bg + kt * 32;
        gload_lds16(a0,           &As[buf][w * 512]);
        gload_lds16(a0 + 64 * K,  &As[buf][w * 512 + 2048]);
        gload_lds16(b0,           &Bs[buf][w * 512]);
        gload_lds16(b0 + 64 * K,  &Bs[buf][w * 512 + 2048]);
    };

    f32x4 acc[4][4] = {};
    stage(0, 0);
    __syncthreads();

    for (int kt = 0; kt < K / 32; ++kt) {
        const int cur = kt & 1;
        if (kt + 1 < K / 32) stage(cur ^ 1, kt + 1);
        half8 af[4], bf[4];
#pragma unroll
        for (int mi = 0; mi < 4; ++mi)
            af[mi] = *(const half8*)&As[cur][(wr * 64 + mi * 16 + lr) * 32 + lg * 8];
#pragma unroll
        for (int ni = 0; ni < 4; ++ni)
            bf[ni] = *(const half8*)&Bs[cur][(wc * 64 + ni * 16 + lr) * 32 + lg * 8];
#pragma unroll
        for (int mi = 0; mi < 4; ++mi)
#pragma unroll
            for (int ni = 0; ni < 4; ++ni)
                acc[mi][ni] = __builtin_amdgcn_mfma_f32_16x16x32_f16(af[mi], bf[ni], acc[mi][ni], 0, 0, 0);
        __syncthreads();
    }

    if (MODE == 0) {
        _Float16* outp = (_Float16*)outbase + (size_t)blockIdx.z * (8192u * 1024u);
        const float scale = (blockIdx.z == 0) ? 0.18033688f : 1.0f;  // (1/8)*log2(e) for Q
        const bool vmode = (blockIdx.z == 2);
#pragma unroll
        for (int mi = 0; mi < 4; ++mi)
#pragma unroll
            for (int ni = 0; ni < 4; ++ni)
#pragma unroll
                for (int r = 0; r < 4; ++r) {
                    int row = brow + wr * 64 + mi * 16 + lg * 4 + r;   // b*2048+s
                    int col = bcol + wc * 64 + ni * 16 + lr;           // h*64+d
                    int b = row >> 11, s = row & 2047;
                    int h = col >> 6,  d = col & 63;
                    size_t idx = vmode ? ((((size_t)b * 16 + h) * 64 + d) * 2048 + s)
                                       : ((((size_t)b * 16 + h) * 2048 + s) * 64 + d);
                    outp[idx] = (_Float16)(acc[mi][ni][r] * scale);
                }
    } else {
        float* outp = (float*)outbase;
#pragma unroll
        for (int mi = 0; mi < 4; ++mi)
#pragma unroll
            for (int ni = 0; ni < 4; ++ni)
#pragma unroll
                for (int r = 0; r < 4; ++r) {
                    int row = brow + wr * 64 + mi * 16 + lg * 4 + r;
                    int col = bcol + wc * 64 + ni * 16 + lr;
                    outp[(size_t)row * 1024 + col] = acc[mi][ni][r];
                }
    }
}

// ---------------- flash attention (swapped-operand, swizzled LDS) ----------------
// grid (32, 64): x = q-block (64 rows), y = b*16+h. 256 threads, 4 waves,
// wave owns 16 q rows. KV tiles 64 keys, double-buffered LDS via global_load_lds
// with XOR-swizzled layout (pre-swizzled global source).
__global__ void attn_kernel(const _Float16* __restrict__ Q,
                            const _Float16* __restrict__ Kx,
                            const _Float16* __restrict__ Vt,
                            _Float16* __restrict__ Ctx)
{
    __shared__ _Float16 Ks[2][64 * 64];   // [key][d] swizzled
    __shared__ _Float16 Vs[2][64 * 64];   // [d][key] swizzled (V pre-transposed in HBM)
    __shared__ _Float16 Ps[4][16 * 80];   // per-wave P [q][key] padded to 80

    const int tid = threadIdx.x, lane = tid & 63, w = tid >> 6;
    const int lr = lane & 15, lg = lane >> 4;
    const int bh = blockIdx.y, qblk = blockIdx.x;

    const _Float16* Qp  = Q  + ((size_t)bh * 2048 + qblk * 64) * 64;
    const _Float16* Kp  = Kx + (size_t)bh * 2048 * 64;
    const _Float16* Vtp = Vt + (size_t)bh * 64 * 2048;

    // staging: lane's 16B chunk at linear LDS offset (w*1024 + lane*16) within a
    // 4KB half-tile; row = w*8 + (lane>>3), colbyte = (lane&7)*16, source column
    // pre-XOR'd so swizzled reads see logical data.
    const int srow = (w << 3) + (lane >> 3);                 // 0..31
    const int sco  = (((lane & 7) ^ (lane >> 3)) << 3);      // halves
    const _Float16* Kst = Kp  + (size_t)srow * 64   + sco;
    const _Float16* Vst = Vtp + (size_t)srow * 2048 + sco;

    const int swz = (lr & 7) << 3;   // XOR mask (half-index domain) for reads

    // Q fragment (B-operand); (1/8)*log2e already folded in at GEMM
    half8 qf[2];
#pragma unroll
    for (int kk = 0; kk < 2; ++kk)
        qf[kk] = *(const half8*)(Qp + (w * 16 + lr) * 64 + kk * 32 + lg * 8);

    f32x4 cacc[4] = {};          // ctx^T: [d = 16ni+4lg+r][q = lr]
    float m = -1e30f, l = 0.f;   // per-lane (its q row), log2 domain

    auto stage = [&](int buf, int t) {
        gload_lds16(Kst + (size_t)(t * 64)      * 64, &Ks[buf][w * 512]);
        gload_lds16(Kst + (size_t)(t * 64 + 32) * 64, &Ks[buf][2048 + w * 512]);
        gload_lds16(Vst + t * 64,                      &Vs[buf][w * 512]);
        gload_lds16(Vst + 32 * 2048 + t * 64,          &Vs[buf][2048 + w * 512]);
    };

    stage(0, 0);
    __syncthreads();

    for (int t = 0; t < 32; ++t) {
        const int cur = t & 1;
        if (t < 31) stage(cur ^ 1, t + 1);   // drains at end-of-tile barrier

        // S^T = K·Q^T : sf[ni] = scores for keys 16ni+4lg+r, q = w*16+lr (log2 units)
        f32x4 sf[4];
#pragma unroll
        for (int ni = 0; ni < 4; ++ni) {
            const int row = 16 * ni + lr;
            half8 k0 = *(const half8*)&Ks[cur][row * 64 + ((8 * lg) ^ swz)];
            half8 k1 = *(const half8*)&Ks[cur][row * 64 + ((32 + 8 * lg) ^ swz)];
            f32x4 z = {};
            z = __builtin_amdgcn_mfma_f32_16x16x32_f16(k0, qf[0], z, 0, 0, 0);
            z = __builtin_amdgcn_mfma_f32_16x16x32_f16(k1, qf[1], z, 0, 0, 0);
            sf[ni] = z;
        }

        // online softmax: local 16-max + 2 shfl over the lg dimension
        float pmax = sf[0][0];
#pragma unroll
        for (int ni = 0; ni < 4; ++ni)
#pragma unroll
            for (int r = 0; r < 4; ++r) pmax = fmaxf(pmax, sf[ni][r]);
        pmax = fmaxf(pmax, __shfl_xor(pmax, 16));
        pmax = fmaxf(pmax, __shfl_xor(pmax, 32));

        if (!__all(pmax <= m + 8.0f)) {      // defer-max: P bounded by 2^8
            float mn = fmaxf(m, pmax);
            float sc = __builtin_amdgcn_exp2f(m - mn);
#pragma unroll
            for (int ni = 0; ni < 4; ++ni)
#pragma unroll
                for (int r = 0; r < 4; ++r) cacc[ni][r] *= sc;
            l *= sc;
            m = mn;
        }

        float rsum = 0.f;
#pragma unroll
        for (int ni = 0; ni < 4; ++ni)
#pragma unroll
            for (int r = 0; r < 4; ++r) {
                float p = __builtin_amdgcn_exp2f(sf[ni][r] - m);
                sf[ni][r] = p;
                rsum += p;
            }
        rsum += __shfl_xor(rsum, 16);
        rsum += __shfl_xor(rsum, 32);
        l += rsum;

        // pack P (fp16) into per-wave LDS: row q=lr, keys 16ni+4lg+0..3
#pragma unroll
        for (int ni = 0; ni < 4; ++ni) {
            union { half4v h4; unsigned int u[2]; } p4;
            p4.u[0] = __builtin_bit_cast(unsigned int,
                        __builtin_amdgcn_cvt_pkrtz(sf[ni][0], sf[ni][1]));
            p4.u[1] = __builtin_bit_cast(unsigned int,
                        __builtin_amdgcn_cvt_pkrtz(sf[ni][2], sf[ni][3]));
            *(half4v*)&Ps[w][lr * 80 + 16 * ni + 4 * lg] = p4.h4;
        }

        // PV (swapped): cacc[ni] += Vt-frag(row=d) x P-frag(col=q)
        half8 pf0 = *(const half8*)&Ps[w][lr * 80 + 8 * lg];
        half8 pf1 = *(const half8*)&Ps[w][lr * 80 + 32 + 8 * lg];
#pragma unroll
        for (int ni = 0; ni < 4; ++ni) {
            const int row = 16 * ni + lr;
            half8 v0 = *(const half8*)&Vs[cur][row * 64 + ((8 * lg) ^ swz)];
            half8 v1 = *(const half8*)&Vs[cur][row * 64 + ((32 + 8 * lg) ^ swz)];
            cacc[ni] = __builtin_amdgcn_mfma_f32_16x16x32_f16(v0, pf0, cacc[ni], 0, 0, 0);
            cacc[ni] = __builtin_amdgcn_mfma_f32_16x16x32_f16(v1, pf1, cacc[ni], 0, 0, 0);
        }

        __syncthreads();
    }

    // epilogue: lane holds ctx^T[d][q=w*16+lr]; write ctx[b][s][h*64+d] fp16
    const float inv = 1.0f / l;
    _Float16* Cp = Ctx + ((size_t)(bh >> 4) * 2048 + qblk * 64 + w * 16 + lr) * 1024 + (bh & 15) * 64;
#pragma unroll
    for (int ni = 0; ni < 4; ++ni) {
        half4v o4;
#pragma unroll
        for (int r = 0; r < 4; ++r) o4[r] = (_Float16)(cacc[ni][r] * inv);
        *(half4v*)&Cp[16 * ni + 4 * lg] = o4;
    }
}

extern "C" void kernel_launch(void* const* d_in, const int* in_sizes, int n_in,
                              void* d_out, int out_size, void* d_ws, size_t ws_size,
                              hipStream_t stream)
{
    const float* X  = (const float*)d_in[0];
    const float* Wq = (const float*)d_in[1];
    const float* Wk = (const float*)d_in[2];
    const float* Wv = (const float*)d_in[3];
    const float* Wo = (const float*)d_in[4];

    // workspace layout (halves): Xh[8M] | Wh[4M] | QKV[24M]; Ctx aliases Xh
    if (ws_size < (size_t)(8 + 4 + 24) * 1024 * 1024 * 2) return;
    _Float16* Xh  = (_Float16*)d_ws;
    _Float16* Wh  = Xh + (size_t)8 * 1024 * 1024;
    _Float16* QKV = Wh + (size_t)4 * 1024 * 1024;
    _Float16* Ctx = Xh;  // reuse after QKV GEMM has consumed Xh

    cvt_f32_f16<<<8192, 256, 0, stream>>>(X,  Xh,            2097152);
    cvt_f32_f16<<<1024, 256, 0, stream>>>(Wq, Wh,            262144);
    cvt_f32_f16<<<1024, 256, 0, stream>>>(Wk, Wh + 1048576,  262144);
    cvt_f32_f16<<<1024, 256, 0, stream>>>(Wv, Wh + 2097152,  262144);
    cvt_f32_f16<<<1024, 256, 0, stream>>>(Wo, Wh + 3145728,  262144);

    // Q,K,V projections (z = 0,1,2); Q pre-scaled, V written transposed
    gemm_nt<0><<<dim3(64, 8, 3), 256, 0, stream>>>(Xh, Wh, QKV);

    // flash attention
    attn_kernel<<<dim3(32, 64), 256, 0, stream>>>(QKV, QKV + 8388608, QKV + 16777216, Ctx);

    // output projection -> fp32 d_out
    gemm_nt<1><<<dim3(64, 8, 1), 256, 0, stream>>>(Ctx, Wh + 3145728, d_out);
}

// Round 4
// 214.911 us; speedup vs baseline: 1.6933x; 1.2681x over previous
//
#include <hip/hip_runtime.h>

typedef _Float16 half8 __attribute__((ext_vector_type(8)));
typedef _Float16 half4v __attribute__((ext_vector_type(4)));
typedef float f32x4 __attribute__((ext_vector_type(4)));
typedef float f32x16 __attribute__((ext_vector_type(16)));

__device__ __forceinline__ void gload_lds16(const _Float16* g, _Float16* l) {
    __builtin_amdgcn_global_load_lds(
        (const __attribute__((address_space(1))) void*)g,
        (__attribute__((address_space(3))) void*)l,
        16, 0, 0);
}

// ---------------- fp32 -> fp16 convert (vectorized) ----------------
__global__ void cvt_f32_f16(const float* __restrict__ src, _Float16* __restrict__ dst, int n4) {
    int i = blockIdx.x * blockDim.x + threadIdx.x;
    if (i >= n4) return;
    f32x4 v = ((const f32x4*)src)[i];
    half4v h;
    h[0] = (_Float16)v[0]; h[1] = (_Float16)v[1];
    h[2] = (_Float16)v[2]; h[3] = (_Float16)v[3];
    ((half4v*)dst)[i] = h;
}

// ---------------- NT GEMM: C[M,N] = A[M,K] * B[N,K]^T ----------------
// MODE 0: QKV — half out; z=0: Q [b,h,s,d] scaled (1/8)*log2e; z=1: K [b,h,s,d];
//         z=2: V^T [b,h,d,s] via LDS-transposed coalesced epilogue
// MODE 1: O-proj — float out, row-major [8192,1024]
template<int MODE>
__global__ void gemm_nt(const _Float16* __restrict__ A,
                        const _Float16* __restrict__ Wbase,
                        void* __restrict__ outbase)
{
    constexpr int K = 1024;
    __shared__ _Float16 As[2][128 * 32];
    __shared__ _Float16 Bs[2][128 * 32];

    const int tid  = threadIdx.x;
    const int lane = tid & 63;
    const int w    = tid >> 6;
    const int wr   = w >> 1, wc = w & 1;
    const int lr   = lane & 15, lg = lane >> 4;
    const int brow = blockIdx.x * 128;
    const int bcol = blockIdx.y * 128;

    const _Float16* Bw = Wbase + (MODE == 0 ? (size_t)blockIdx.z * (1024u * 1024u) : 0);

    const int srow = w * 16 + (lane >> 2);
    const int scol = (lane & 3) * 8;
    const _Float16* Ag = A  + (size_t)(brow + srow) * K + scol;
    const _Float16* Bg = Bw + (size_t)(bcol + srow) * K + scol;

    auto stage = [&](int buf, int kt) {
        const _Float16* a0 = Ag + kt * 32;
        const _Float16* b0 = Bg + kt * 32;
        gload_lds16(a0,           &As[buf][w * 512]);
        gload_lds16(a0 + 64 * K,  &As[buf][w * 512 + 2048]);
        gload_lds16(b0,           &Bs[buf][w * 512]);
        gload_lds16(b0 + 64 * K,  &Bs[buf][w * 512 + 2048]);
    };

    f32x4 acc[4][4] = {};
    stage(0, 0);
    __syncthreads();

    for (int kt = 0; kt < K / 32; ++kt) {
        const int cur = kt & 1;
        if (kt + 1 < K / 32) stage(cur ^ 1, kt + 1);
        half8 af[4], bf[4];
#pragma unroll
        for (int mi = 0; mi < 4; ++mi)
            af[mi] = *(const half8*)&As[cur][(wr * 64 + mi * 16 + lr) * 32 + lg * 8];
#pragma unroll
        for (int ni = 0; ni < 4; ++ni)
            bf[ni] = *(const half8*)&Bs[cur][(wc * 64 + ni * 16 + lr) * 32 + lg * 8];
#pragma unroll
        for (int mi = 0; mi < 4; ++mi)
#pragma unroll
            for (int ni = 0; ni < 4; ++ni)
                acc[mi][ni] = __builtin_amdgcn_mfma_f32_16x16x32_f16(af[mi], bf[ni], acc[mi][ni], 0, 0, 0);
        __syncthreads();
    }

    if (MODE == 0) {
        _Float16* outp = (_Float16*)outbase + (size_t)blockIdx.z * (8192u * 1024u);
        if (blockIdx.z == 2) {
            // V^T epilogue: transpose 128x128 tile through LDS, coalesced out.
            _Float16* Ts = &As[0][0];  // 8192 halves scratch = [64][128] (+XOR swizzle)
#pragma unroll
            for (int p = 0; p < 2; ++p) {
                if (wc == p) {
#pragma unroll
                    for (int mi = 0; mi < 4; ++mi)
#pragma unroll
                        for (int ni = 0; ni < 4; ++ni) {
                            int drow = ni * 16 + lr;            // local d (0..63)
                            int s0   = wr * 64 + mi * 16 + lg * 4;
                            half4v o;
#pragma unroll
                            for (int r = 0; r < 4; ++r) o[r] = (_Float16)acc[mi][ni][r];
                            int byteoff = drow * 256 + s0 * 2;
                            byteoff ^= (drow & 7) << 4;
                            *(half4v*)((char*)Ts + byteoff) = o;
                        }
                }
                __syncthreads();
                {
                    int row   = tid >> 2;          // local d row 0..63
                    int cbase = (tid & 3) * 4;     // 16B-chunk base (of 16)
                    int gd = bcol + p * 64 + row;  // global col = h*64+dd
                    int h = gd >> 6, dd = gd & 63;
                    int b = brow >> 11, sseq = brow & 2047;
                    _Float16* gout = outp + (((size_t)b * 16 + h) * 64 + dd) * 2048 + sseq;
#pragma unroll
                    for (int j = 0; j < 4; ++j) {
                        int c  = cbase + j;
                        int lc = c ^ (row & 7);
                        half8 v = *(const half8*)&Ts[row * 128 + lc * 8];
                        *(half8*)&gout[c * 8] = v;
                    }
                }
                __syncthreads();
            }
        } else {
            const float scale = (blockIdx.z == 0) ? 0.18033688f : 1.0f;  // (1/8)*log2(e)
#pragma unroll
            for (int mi = 0; mi < 4; ++mi)
#pragma unroll
                for (int ni = 0; ni < 4; ++ni)
#pragma unroll
                    for (int r = 0; r < 4; ++r) {
                        int row = brow + wr * 64 + mi * 16 + lg * 4 + r;   // b*2048+s
                        int col = bcol + wc * 64 + ni * 16 + lr;           // h*64+d
                        int b = row >> 11, s = row & 2047;
                        int h = col >> 6,  d = col & 63;
                        outp[(((size_t)b * 16 + h) * 2048 + s) * 64 + d] =
                            (_Float16)(acc[mi][ni][r] * scale);
                    }
        }
    } else {
        float* outp = (float*)outbase;
#pragma unroll
        for (int mi = 0; mi < 4; ++mi)
#pragma unroll
            for (int ni = 0; ni < 4; ++ni)
#pragma unroll
                for (int r = 0; r < 4; ++r) {
                    int row = brow + wr * 64 + mi * 16 + lg * 4 + r;
                    int col = bcol + wc * 64 + ni * 16 + lr;
                    outp[(size_t)row * 1024 + col] = acc[mi][ni][r];
                }
    }
}

// ---------------- flash attention v4: 32x32 MFMA, in-register P ----------------
// grid (16, 64): x = q-block (128 rows), y = b*16+h. 4 waves x 32 q-rows.
// KV tiles of 64 keys, reg-staged double-buffered LDS, 144B padded rows.
__global__ __launch_bounds__(256, 4)
void attn_kernel(const _Float16* __restrict__ Q,
                 const _Float16* __restrict__ Kx,
                 const _Float16* __restrict__ Vt,
                 _Float16* __restrict__ Ctx)
{
    __shared__ _Float16 Ks[2][64 * 72];   // [key][d], stride 72 halves
    __shared__ _Float16 Vs[2][64 * 72];   // [d][key], stride 72 halves

    const int tid = threadIdx.x, lane = tid & 63, w = tid >> 6;
    const int l31 = lane & 31, hi = lane >> 5;
    const int bh = blockIdx.y, qblk = blockIdx.x;

    const _Float16* Qp  = Q  + ((size_t)bh * 2048 + qblk * 128) * 64;
    const _Float16* Kp  = Kx + (size_t)bh * 2048 * 64;
    const _Float16* Vtp = Vt + (size_t)bh * 64 * 2048;

    // Q frags (B-operand): qf[ks] = Q[w*32+l31][16ks+8hi .. +7], pre-scaled by log2e/8
    half8 qf[4];
#pragma unroll
    for (int ks = 0; ks < 4; ++ks)
        qf[ks] = *(const half8*)(Qp + (size_t)(w * 32 + l31) * 64 + ks * 16 + hi * 8);

    // staging: thread -> 2 chunks per matrix; chunk c: row c*32+(tid>>3), col (tid&7)*8
    const int srow = tid >> 3;
    const int scol = (tid & 7) * 8;
    const _Float16* Kg0 = Kp  + (size_t)srow * 64   + scol;
    const _Float16* Vg0 = Vtp + (size_t)srow * 2048 + scol;
    const int ldso = srow * 72 + scol;

    f32x16 cacc[2] = {};
    float m = -1e30f, l = 0.f;

    half8 kr0, kr1, vr0, vr1;
    // prologue: tile 0
    kr0 = *(const half8*)(Kg0);
    kr1 = *(const half8*)(Kg0 + 32 * 64);
    vr0 = *(const half8*)(Vg0);
    vr1 = *(const half8*)(Vg0 + 32 * 2048);
    *(half8*)&Ks[0][ldso]           = kr0;
    *(half8*)&Ks[0][ldso + 32 * 72] = kr1;
    *(half8*)&Vs[0][ldso]           = vr0;
    *(half8*)&Vs[0][ldso + 32 * 72] = vr1;
    __syncthreads();

    for (int t = 0; t < 32; ++t) {
        const int cur = t & 1;
        if (t < 31) {   // issue K(t+1) loads early
            kr0 = *(const half8*)(Kg0 + (size_t)(t + 1) * 4096);
            kr1 = *(const half8*)(Kg0 + (size_t)(t + 1) * 4096 + 32 * 64);
        }

        // S^T = K * Q^T : sf[kt][reg] = S[key=32kt+(reg&3)+8*(reg>>2)+4hi][q=l31]
        f32x16 sf[2];
        __builtin_amdgcn_s_setprio(1);
#pragma unroll
        for (int kt = 0; kt < 2; ++kt) {
            f32x16 z = {};
#pragma unroll
            for (int ks = 0; ks < 4; ++ks) {
                half8 kf = *(const half8*)&Ks[cur][(kt * 32 + l31) * 72 + ks * 16 + hi * 8];
                z = __builtin_amdgcn_mfma_f32_32x32x16_f16(kf, qf[ks], z, 0, 0, 0);
            }
            sf[kt] = z;
        }
        __builtin_amdgcn_s_setprio(0);

        if (t < 31) {   // write K(t+1), then issue V(t+1) loads
            *(half8*)&Ks[cur ^ 1][ldso]           = kr0;
            *(half8*)&Ks[cur ^ 1][ldso + 32 * 72] = kr1;
            vr0 = *(const half8*)(Vg0 + (t + 1) * 64);
            vr1 = *(const half8*)(Vg0 + (t + 1) * 64 + 32 * 2048);
        }

        // online softmax (log2 domain)
        float pmax = -1e30f;
#pragma unroll
        for (int kt = 0; kt < 2; ++kt)
#pragma unroll
            for (int r = 0; r < 16; ++r) pmax = fmaxf(pmax, sf[kt][r]);
        pmax = fmaxf(pmax, __shfl_xor(pmax, 32, 64));

        if (!__all(pmax <= m + 8.0f)) {   // defer-max: P bounded by 2^8
            float mn = fmaxf(m, pmax);
            float sc = __builtin_amdgcn_exp2f(m - mn);
            cacc[0] = cacc[0] * sc;
            cacc[1] = cacc[1] * sc;
            l *= sc;
            m = mn;
        }

        float rsum = 0.f;
#pragma unroll
        for (int kt = 0; kt < 2; ++kt)
#pragma unroll
            for (int r = 0; r < 16; ++r) {
                float p = __builtin_amdgcn_exp2f(sf[kt][r] - m);
                sf[kt][r] = p;
                rsum += p;
            }
        rsum += __shfl_xor(rsum, 32, 64);
        l += rsum;

        // pack P to fp16 pairs: uq[kt][qd][w2] = regs 4qd+2w2, 4qd+2w2+1
        unsigned uq[2][4][2];
#pragma unroll
        for (int kt = 0; kt < 2; ++kt)
#pragma unroll
            for (int qd = 0; qd < 4; ++qd)
#pragma unroll
                for (int w2 = 0; w2 < 2; ++w2)
                    uq[kt][qd][w2] = __builtin_bit_cast(unsigned,
                        __builtin_amdgcn_cvt_pkrtz(sf[kt][4 * qd + 2 * w2],
                                                   sf[kt][4 * qd + 2 * w2 + 1]));

        // assemble PV B-frags: bf[ks] halves e -> key 16ks+8hi+e
        half8 bf[4];
#pragma unroll
        for (int ks = 0; ks < 4; ++ks) {
            const int kt = ks >> 1, k1 = ks & 1;
            union { half8 h; unsigned u[4]; } bu;
#pragma unroll
            for (int w2 = 0; w2 < 2; ++w2) {
                unsigned a = uq[kt][2 * k1][w2];      // quad for lo targets
                unsigned b = uq[kt][2 * k1 + 1][w2];  // quad for hi targets
                unsigned send = hi ? a : b;
                unsigned recv = (unsigned)__shfl_xor((int)send, 32, 64);
                bu.u[w2]     = hi ? recv : a;   // lo-source halves (e 0..3)
                bu.u[2 + w2] = hi ? b : recv;   // hi-source halves (e 4..7)
            }
            bf[ks] = bu.h;
        }

        // PV: cacc[dt] += V^T-frag x P-frag
        __builtin_amdgcn_s_setprio(1);
#pragma unroll
        for (int dt = 0; dt < 2; ++dt)
#pragma unroll
            for (int ks = 0; ks < 4; ++ks) {
                half8 vf = *(const half8*)&Vs[cur][(dt * 32 + l31) * 72 + ks * 16 + hi * 8];
                cacc[dt] = __builtin_amdgcn_mfma_f32_32x32x16_f16(vf, bf[ks], cacc[dt], 0, 0, 0);
            }
        __builtin_amdgcn_s_setprio(0);

        if (t < 31) {   // write V(t+1)
            *(half8*)&Vs[cur ^ 1][ldso]           = vr0;
            *(half8*)&Vs[cur ^ 1][ldso + 32 * 72] = vr1;
        }
        __syncthreads();
    }

    // epilogue: cacc[dt][reg] = ctx^T[d=32dt+(reg&3)+8*(reg>>2)+4hi][q=w*32+l31]
    const float inv = 1.0f / l;
    const int s = qblk * 128 + w * 32 + l31;
    _Float16* Cp = Ctx + ((size_t)(bh >> 4) * 2048 + s) * 1024 + (bh & 15) * 64;
#pragma unroll
    for (int dt = 0; dt < 2; ++dt)
#pragma unroll
        for (int qd = 0; qd < 4; ++qd) {
            half4v o;
#pragma unroll
            for (int j = 0; j < 4; ++j) o[j] = (_Float16)(cacc[dt][4 * qd + j] * inv);
            *(half4v*)&Cp[dt * 32 + qd * 8 + hi * 4] = o;
        }
}

extern "C" void kernel_launch(void* const* d_in, const int* in_sizes, int n_in,
                              void* d_out, int out_size, void* d_ws, size_t ws_size,
                              hipStream_t stream)
{
    const float* X  = (const float*)d_in[0];
    const float* Wq = (const float*)d_in[1];
    const float* Wk = (const float*)d_in[2];
    const float* Wv = (const float*)d_in[3];
    const float* Wo = (const float*)d_in[4];

    // workspace layout (halves): Xh[8M] | Wh[4M] | QKV[24M]; Ctx aliases Xh
    if (ws_size < (size_t)(8 + 4 + 24) * 1024 * 1024 * 2) return;
    _Float16* Xh  = (_Float16*)d_ws;
    _Float16* Wh  = Xh + (size_t)8 * 1024 * 1024;
    _Float16* QKV = Wh + (size_t)4 * 1024 * 1024;
    _Float16* Ctx = Xh;  // reuse after QKV GEMM has consumed Xh

    cvt_f32_f16<<<8192, 256, 0, stream>>>(X,  Xh,            2097152);
    cvt_f32_f16<<<1024, 256, 0, stream>>>(Wq, Wh,            262144);
    cvt_f32_f16<<<1024, 256, 0, stream>>>(Wk, Wh + 1048576,  262144);
    cvt_f32_f16<<<1024, 256, 0, stream>>>(Wv, Wh + 2097152,  262144);
    cvt_f32_f16<<<1024, 256, 0, stream>>>(Wo, Wh + 3145728,  262144);

    // Q,K,V projections (z = 0,1,2); Q pre-scaled, V written transposed
    gemm_nt<0><<<dim3(64, 8, 3), 256, 0, stream>>>(Xh, Wh, QKV);

    // flash attention
    attn_kernel<<<dim3(16, 64), 256, 0, stream>>>(QKV, QKV + 8388608, QKV + 16777216, Ctx);

    // output projection -> fp32 d_out
    gemm_nt<1><<<dim3(64, 8, 1), 256, 0, stream>>>(Ctx, Wh + 3145728, d_out);
}